// Round 2
// baseline (4492.003 us; speedup 1.0000x reference)
//
#include <hip/hip_runtime.h>
#include <hip/hip_bf16.h>
#include <math.h>

#define EPSBN 1e-5f

__device__ __forceinline__ float gelu_f(float x) {
    return 0.5f * x * (1.0f + erff(x * 0.70710678118654752f));
}

// ---------------- weight prep: [G][oc][ic][9] -> [G][ic][9][oc] ----------------
__global__ void wprep_region_k(const float* __restrict__ w, float* __restrict__ wt, long total) {
    for (long i = (long)blockIdx.x * blockDim.x + threadIdx.x; i < total;
         i += (long)gridDim.x * blockDim.x) {
        int k = (int)(i % 9); long t = i / 9;
        int ic = (int)(t % 192); t /= 192;
        int oc = (int)(t % 192); long g = t / 192;
        wt[((g * 192 + ic) * 9 + k) * 192 + oc] = w[i];
    }
}

// [OC][IC][KK] -> [IC][KK][OC]
__global__ void wprep_small_k(const float* __restrict__ w, float* __restrict__ wt,
                              int OC, int IC, int KK) {
    long total = (long)OC * IC * KK;
    for (long i = (long)blockIdx.x * blockDim.x + threadIdx.x; i < total;
         i += (long)gridDim.x * blockDim.x) {
        int k = (int)(i % KK); long t = i / KK;
        int ic = (int)(t % IC); int oc = (int)(t / IC);
        wt[((long)ic * KK + k) * OC + oc] = w[i];
    }
}

// ---------------- conv1: 3->192, 4x4 stride 4, BN+GELU ----------------
__global__ __launch_bounds__(256) void conv1_k(
        const float* __restrict__ x, const float* __restrict__ w,
        const float* __restrict__ bg, const float* __restrict__ bb,
        const float* __restrict__ bm, const float* __restrict__ bv,
        float* __restrict__ out) {
    long idx = (long)blockIdx.x * 256 + threadIdx.x;
    if (idx >= (long)64 * 192 * 56 * 56) return;
    int ox = (int)(idx % 56); long t = idx / 56;
    int oy = (int)(t % 56); t /= 56;
    int oc = (int)(t % 192); int b = (int)(t / 192);
    const float* xb = x + (long)b * 3 * 224 * 224;
    const float* wp = w + oc * 48;
    float acc = 0.f;
    #pragma unroll
    for (int c = 0; c < 3; c++) {
        #pragma unroll
        for (int ky = 0; ky < 4; ky++) {
            const float* row = xb + ((long)c * 224 + (4 * oy + ky)) * 224 + 4 * ox;
            const float* wr = wp + (c * 4 + ky) * 4;
            acc += row[0] * wr[0] + row[1] * wr[1] + row[2] * wr[2] + row[3] * wr[3];
        }
    }
    float inv = bg[oc] * rsqrtf(bv[oc] + EPSBN);
    float bet = bb[oc] - bm[oc] * inv;
    out[idx] = gelu_f(acc * inv + bet);
}

// ---------------- region conv: per-tile 3x3 SAME, BN+GELU+residual, IN-PLACE ----------------
// block = g*B + b ; 192 threads, thread = oc.
// Safe in-place: each block reads its whole tile to LDS, syncs, then overwrites it.
// wmode=1: wt layout [g][ic][9][oc] (coalesced); wmode=0: original [g][oc][ic][9].
__global__ __launch_bounds__(192) void region_k(
        float* __restrict__ buf, const float* __restrict__ w,
        const float* __restrict__ pg, const float* __restrict__ pb,
        const float* __restrict__ pm, const float* __restrict__ pv,
        int B, int gw, int W, int wmode) {
    __shared__ float tile[192 * 52];   // stride 52: 208B rows, 16B aligned
    int bid = blockIdx.x;
    int b = bid % B;
    int g = bid / B;
    int gy = g / gw, gx = g % gw;
    int Y0 = gy * 7, X0 = gx * 7;
    const int tid = threadIdx.x;
    float* inb = buf + (long)b * 192 * W * W;
    for (int i = tid; i < 192 * 49; i += 192) {
        int ic = i / 49, p = i % 49;
        int y = p / 7, xx = p % 7;
        tile[ic * 52 + p] = inb[((long)ic * W + (Y0 + y)) * W + (X0 + xx)];
    }
    __syncthreads();
    const int oc = tid;
    float acc[49];
    #pragma unroll
    for (int i = 0; i < 49; i++) acc[i] = 0.f;
    const float* wbT = w + ((long)g * 192 * 9) * 192 + oc;           // wmode=1
    const float* wbD = w + (((long)g * 192 + oc) * 192) * 9;         // wmode=0
    for (int ic = 0; ic < 192; ic++) {
        float p[49];
        #pragma unroll
        for (int j = 0; j < 49; j++) p[j] = tile[ic * 52 + j];
        float wv[9];
        if (wmode) {
            #pragma unroll
            for (int k = 0; k < 9; k++) wv[k] = wbT[((long)ic * 9 + k) * 192];
        } else {
            #pragma unroll
            for (int k = 0; k < 9; k++) wv[k] = wbD[(long)ic * 9 + k];
        }
        #pragma unroll
        for (int ky = 0; ky < 3; ky++) {
            #pragma unroll
            for (int kx = 0; kx < 3; kx++) {
                float wk = wv[ky * 3 + kx];
                #pragma unroll
                for (int y = 0; y < 7; y++) {
                    int iy = y + ky - 1;
                    if (iy < 0 || iy >= 7) continue;
                    #pragma unroll
                    for (int xx = 0; xx < 7; xx++) {
                        int ix = xx + kx - 1;
                        if (ix < 0 || ix >= 7) continue;
                        acc[y * 7 + xx] += wk * p[iy * 7 + ix];
                    }
                }
            }
        }
    }
    float sg = pg[g * 192 + oc], sb = pb[g * 192 + oc];
    float sm = pm[g * 192 + oc], sv = pv[g * 192 + oc];
    float inv = sg * rsqrtf(sv + EPSBN);
    float bet = sb - sm * inv;
    float* ob = inb + (long)oc * W * W;
    #pragma unroll
    for (int pp = 0; pp < 49; pp++) {
        float val = gelu_f(acc[pp] * inv + bet) + tile[oc * 52 + pp];
        ob[((long)(Y0 + pp / 7)) * W + (X0 + pp % 7)] = val;
    }
}

// ---------------- conv2: 192->192, 2x2 stride 2, BN+GELU ----------------
// block = (b, oy), 192 threads = oc, acc over 28 ox
__global__ __launch_bounds__(192) void conv2_k(
        const float* __restrict__ in, const float* __restrict__ wt,
        const float* __restrict__ bg, const float* __restrict__ bb,
        const float* __restrict__ bm, const float* __restrict__ bv,
        float* __restrict__ out) {
    int bid = blockIdx.x;
    int oy = bid % 28, b = bid / 28;
    int oc = threadIdx.x;
    float acc[28];
    #pragma unroll
    for (int i = 0; i < 28; i++) acc[i] = 0.f;
    for (int ic = 0; ic < 192; ic++) {
        #pragma unroll
        for (int ky = 0; ky < 2; ky++) {
            const float* row = in + (((long)b * 192 + ic) * 56 + (2 * oy + ky)) * 56;
            float w0 = wt[((ic * 2 + ky) * 2 + 0) * 192 + oc];
            float w1 = wt[((ic * 2 + ky) * 2 + 1) * 192 + oc];
            #pragma unroll
            for (int ox = 0; ox < 28; ox++) {
                float2 iv = *(const float2*)(row + 2 * ox);
                acc[ox] += iv.x * w0 + iv.y * w1;
            }
        }
    }
    float inv = bg[oc] * rsqrtf(bv[oc] + EPSBN);
    float bet = bb[oc] - bm[oc] * inv;
    float* ob = out + (((long)b * 192 + oc) * 28 + oy) * 28;
    #pragma unroll
    for (int ox = 0; ox < 28; ox++) ob[ox] = gelu_f(acc[ox] * inv + bet);
}

// ---------------- conv3: 192->768, 2x2 stride 2, BN, fused transpose store ----------------
// block = ((b*14 + y)*3 + chunk), 256 threads, oc = chunk*256+tid
__global__ __launch_bounds__(256) void conv3_k(
        const float* __restrict__ in, const float* __restrict__ wt,
        const float* __restrict__ bg, const float* __restrict__ bb,
        const float* __restrict__ bm, const float* __restrict__ bv,
        float* __restrict__ out) {
    int bid = blockIdx.x;
    int chunk = bid % 3; int t = bid / 3;
    int y = t % 14; int b = t / 14;
    int oc = chunk * 256 + threadIdx.x;
    float acc[14];
    #pragma unroll
    for (int i = 0; i < 14; i++) acc[i] = 0.f;
    for (int ic = 0; ic < 192; ic++) {
        #pragma unroll
        for (int ky = 0; ky < 2; ky++) {
            const float* row = in + (((long)b * 192 + ic) * 28 + (2 * y + ky)) * 28;
            float w0 = wt[((ic * 2 + ky) * 2 + 0) * 768 + oc];
            float w1 = wt[((ic * 2 + ky) * 2 + 1) * 768 + oc];
            #pragma unroll
            for (int xx = 0; xx < 14; xx++) {
                float2 iv = *(const float2*)(row + 2 * xx);
                acc[xx] += iv.x * w0 + iv.y * w1;
            }
        }
    }
    float inv = bg[oc] * rsqrtf(bv[oc] + EPSBN);
    float bet = bb[oc] - bm[oc] * inv;
    #pragma unroll
    for (int xx = 0; xx < 14; xx++)
        out[((long)b * 196 + y * 14 + xx) * 768 + oc] = acc[xx] * inv + bet;
}

extern "C" void kernel_launch(void* const* d_in, const int* in_sizes, int n_in,
                              void* d_out, int out_size, void* d_ws, size_t ws_size,
                              hipStream_t stream) {
    const float* x   = (const float*)d_in[0];
    const float* w1  = (const float*)d_in[1];
    const float* b1g = (const float*)d_in[2];
    const float* b1b = (const float*)d_in[3];
    const float* b1m = (const float*)d_in[4];
    const float* b1v = (const float*)d_in[5];
    const float* r1w = (const float*)d_in[6];
    const float* r1g = (const float*)d_in[7];
    const float* r1b = (const float*)d_in[8];
    const float* r1m = (const float*)d_in[9];
    const float* r1v = (const float*)d_in[10];
    const float* w2  = (const float*)d_in[11];
    const float* b2g = (const float*)d_in[12];
    const float* b2b = (const float*)d_in[13];
    const float* b2m = (const float*)d_in[14];
    const float* b2v = (const float*)d_in[15];
    const float* r2w = (const float*)d_in[16];
    const float* r2g = (const float*)d_in[17];
    const float* r2b = (const float*)d_in[18];
    const float* r2m = (const float*)d_in[19];
    const float* r2v = (const float*)d_in[20];
    const float* w3  = (const float*)d_in[21];
    const float* b3g = (const float*)d_in[22];
    const float* b3b = (const float*)d_in[23];
    const float* b3m = (const float*)d_in[24];
    const float* b3v = (const float*)d_in[25];
    float* out = (float*)d_out;

    char* ws = (char*)d_ws;
    // Required buffers (in-place region convs; h1 also serves as region1 out, h2 as region2 out):
    const size_t SZ_H1   = 154140672UL;  // 64*192*56*56*4
    const size_t SZ_H2   = 38535168UL;   // 64*192*28*28*4
    const size_t SZ_CWT2 = 589824UL;     // 192*192*4*4
    const size_t SZ_CWT3 = 2359296UL;    // 768*192*4*4
    const size_t SZ_RWT1 = 84934656UL;   // 64*192*192*9*4
    const size_t SZ_RWT2 = 21233664UL;   // 16*192*192*9*4

    float* h1   = (float*)(ws);
    float* h2   = (float*)(ws + SZ_H1);
    float* cwt2 = (float*)(ws + SZ_H1 + SZ_H2);
    float* cwt3 = (float*)(ws + SZ_H1 + SZ_H2 + SZ_CWT2);
    size_t base = SZ_H1 + SZ_H2 + SZ_CWT2 + SZ_CWT3;        // ~195.6 MB

    // Plan A if workspace allows transposed (coalesced) region weights; else Plan B reads
    // original layout (per-thread 9-contiguous floats, L2-amortized over 64 batches/tile).
    int wmode = (ws_size >= base + SZ_RWT1 + SZ_RWT2) ? 1 : 0;
    float* rwt1 = (float*)(ws + base);
    float* rwt2 = (float*)(ws + base + SZ_RWT1);

    wprep_small_k<<<576, 256, 0, stream>>>(w2, cwt2, 192, 192, 4);
    wprep_small_k<<<2304, 256, 0, stream>>>(w3, cwt3, 768, 192, 4);
    if (wmode) {
        wprep_region_k<<<8192, 256, 0, stream>>>(r1w, rwt1, (long)64 * 192 * 192 * 9);
        wprep_region_k<<<2048, 256, 0, stream>>>(r2w, rwt2, (long)16 * 192 * 192 * 9);
    }
    const float* rw1 = wmode ? rwt1 : r1w;
    const float* rw2 = wmode ? rwt2 : r2w;

    conv1_k<<<150528, 256, 0, stream>>>(x, w1, b1g, b1b, b1m, b1v, h1);
    region_k<<<64 * 64, 192, 0, stream>>>(h1, rw1, r1g, r1b, r1m, r1v, 64, 8, 56, wmode);
    conv2_k<<<64 * 28, 192, 0, stream>>>(h1, cwt2, b2g, b2b, b2m, b2v, h2);
    region_k<<<16 * 64, 192, 0, stream>>>(h2, rw2, r2g, r2b, r2m, r2v, 64, 4, 28, wmode);
    conv3_k<<<64 * 14 * 3, 256, 0, stream>>>(h2, cwt3, b3g, b3b, b3m, b3v, out);
}

// Round 3
// 2262.962 us; speedup vs baseline: 1.9850x; 1.9850x over previous
//
#include <hip/hip_runtime.h>
#include <hip/hip_bf16.h>
#include <math.h>

#define EPSBN 1e-5f

typedef short short8 __attribute__((ext_vector_type(8)));
typedef float floatx4 __attribute__((ext_vector_type(4)));

__device__ __forceinline__ float gelu_f(float x) {
    return 0.5f * x * (1.0f + erff(x * 0.70710678118654752f));
}

__device__ __forceinline__ unsigned short f2bf(float f) {
    union { float f; unsigned int u; } c; c.f = f;
    unsigned int u = c.u;
    unsigned int r = (u + 0x7FFFu + ((u >> 16) & 1u)) >> 16;   // RNE
    return (unsigned short)r;
}

// ---------------- weight prep: [G][oc][ic][3][3] fp32 -> [G][oc][t][ic] bf16 ----------------
// o-indexed so WRITES are coalesced; reads are strided but L2-buffered.
__global__ void wprep_bf16_k(const float* __restrict__ w, unsigned short* __restrict__ wb,
                             long total) {
    for (long o = (long)blockIdx.x * blockDim.x + threadIdx.x; o < total;
         o += (long)gridDim.x * blockDim.x) {
        int ic = (int)(o % 192); long t0 = o / 192;
        int t = (int)(t0 % 9); long t1 = t0 / 9;
        int oc = (int)(t1 % 192); long g = t1 / 192;
        wb[o] = f2bf(w[(((size_t)g * 192 + oc) * 192 + ic) * 9 + t]);
    }
}

// [OC][IC][KK] -> [IC][KK][OC]  (fp32, for conv2/conv3)
__global__ void wprep_small_k(const float* __restrict__ w, float* __restrict__ wt,
                              int OC, int IC, int KK) {
    long total = (long)OC * IC * KK;
    for (long i = (long)blockIdx.x * blockDim.x + threadIdx.x; i < total;
         i += (long)gridDim.x * blockDim.x) {
        int k = (int)(i % KK); long t = i / KK;
        int ic = (int)(t % IC); int oc = (int)(t / IC);
        wt[((long)ic * KK + k) * OC + oc] = w[i];
    }
}

// ---------------- conv1: 3->192, 4x4 stride 4, BN+GELU ----------------
__global__ __launch_bounds__(256) void conv1_k(
        const float* __restrict__ x, const float* __restrict__ w,
        const float* __restrict__ bg, const float* __restrict__ bb,
        const float* __restrict__ bm, const float* __restrict__ bv,
        float* __restrict__ out) {
    long idx = (long)blockIdx.x * 256 + threadIdx.x;
    if (idx >= (long)64 * 192 * 56 * 56) return;
    int ox = (int)(idx % 56); long t = idx / 56;
    int oy = (int)(t % 56); t /= 56;
    int oc = (int)(t % 192); int b = (int)(t / 192);
    const float* xb = x + (long)b * 3 * 224 * 224;
    const float* wp = w + oc * 48;
    float acc = 0.f;
    #pragma unroll
    for (int c = 0; c < 3; c++) {
        #pragma unroll
        for (int ky = 0; ky < 4; ky++) {
            const float* row = xb + ((long)c * 224 + (4 * oy + ky)) * 224 + 4 * ox;
            const float* wr = wp + (c * 4 + ky) * 4;
            acc += row[0] * wr[0] + row[1] * wr[1] + row[2] * wr[2] + row[3] * wr[3];
        }
    }
    float inv = bg[oc] * rsqrtf(bv[oc] + EPSBN);
    float bet = bb[oc] - bm[oc] * inv;
    out[idx] = gelu_f(acc * inv + bet);
}

// ---------------- region conv via MFMA (bf16), BN+GELU+residual, IN-PLACE ----------------
// block = g*B + b ; 256 threads = 4 waves. Per-block GEMM: M=192(oc) x N=64(px,49 valid)
// x K=1728 (t-major: k = t*192 + ic). LDS holds padded 9x9x192 bf16 tile, row stride 232
// (464B = 116 words = 20 mod 32 banks -> 2-way = free; 16B aligned for ds_read_b128).
#define TSTRIDE 232
__global__ __launch_bounds__(256) void region_mfma_k(
        float* __restrict__ buf, const unsigned short* __restrict__ wb,
        const float* __restrict__ pg, const float* __restrict__ pb,
        const float* __restrict__ pm, const float* __restrict__ pv,
        int B, int gw, int W) {
    __shared__ unsigned short lds[9 * 9 * TSTRIDE];   // 37584 B
    const int bid = blockIdx.x;
    const int b = bid % B;
    const int g = bid / B;
    const int gy = g / gw, gx = g % gw;
    const int Y0 = gy * 7, X0 = gx * 7;
    const int tid = threadIdx.x;
    const int lane = tid & 63;
    const int wid = tid >> 6;          // 0..3
    const int quad = lane >> 4;        // 0..3
    const int l15 = lane & 15;
    float* inb = buf + (long)b * 192 * W * W;

    // zero LDS (vectorized), then fill interior
    {
        short8* z = (short8*)lds;
        short8 zv = (short8)0;
        for (int i = tid; i < (9 * 9 * TSTRIDE) / 8; i += 256) z[i] = zv;
    }
    __syncthreads();
    for (int i = tid; i < 192 * 49; i += 256) {
        int ic = i / 49, p = i % 49;
        int y = p / 7, xx = p % 7;
        float v = inb[((long)ic * W + (Y0 + y)) * W + (X0 + xx)];
        lds[((y + 1) * 9 + (xx + 1)) * TSTRIDE + ic] = f2bf(v);
    }
    __syncthreads();

    // per-lane N-pixel coords (clamped; cols >=49 discarded)
    int py[4], px[4];
    #pragma unroll
    for (int nt = 0; nt < 4; nt++) {
        int p = nt * 16 + l15; if (p > 48) p = 48;
        py[nt] = p / 7; px[nt] = p % 7;
    }
    // A row base pointers: oc = wid*48 + mt*16 + l15
    const unsigned short* baseA[3];
    #pragma unroll
    for (int mt = 0; mt < 3; mt++) {
        int oc = wid * 48 + mt * 16 + l15;
        baseA[mt] = wb + ((size_t)(g * 192 + oc)) * 9 * 192;
    }

    floatx4 acc[3][4];
    #pragma unroll
    for (int mt = 0; mt < 3; mt++)
        #pragma unroll
        for (int nt = 0; nt < 4; nt++) acc[mt][nt] = (floatx4)0.f;

    for (int t = 0; t < 9; t++) {
        const int ky = t / 3, kx = t % 3;
        int cellb[4];
        #pragma unroll
        for (int nt = 0; nt < 4; nt++)
            cellb[nt] = ((py[nt] + ky) * 9 + (px[nt] + kx)) * TSTRIDE;
        const unsigned short* at0 = baseA[0] + t * 192;
        const unsigned short* at1 = baseA[1] + t * 192;
        const unsigned short* at2 = baseA[2] + t * 192;
        #pragma unroll
        for (int s = 0; s < 6; s++) {
            const int ic0 = s * 32 + quad * 8;
            short8 a0 = *(const short8*)(at0 + ic0);
            short8 a1 = *(const short8*)(at1 + ic0);
            short8 a2 = *(const short8*)(at2 + ic0);
            short8 b0 = *(const short8*)(&lds[cellb[0] + ic0]);
            short8 b1 = *(const short8*)(&lds[cellb[1] + ic0]);
            short8 b2 = *(const short8*)(&lds[cellb[2] + ic0]);
            short8 b3 = *(const short8*)(&lds[cellb[3] + ic0]);
            acc[0][0] = __builtin_amdgcn_mfma_f32_16x16x32_bf16(a0, b0, acc[0][0], 0, 0, 0);
            acc[0][1] = __builtin_amdgcn_mfma_f32_16x16x32_bf16(a0, b1, acc[0][1], 0, 0, 0);
            acc[0][2] = __builtin_amdgcn_mfma_f32_16x16x32_bf16(a0, b2, acc[0][2], 0, 0, 0);
            acc[0][3] = __builtin_amdgcn_mfma_f32_16x16x32_bf16(a0, b3, acc[0][3], 0, 0, 0);
            acc[1][0] = __builtin_amdgcn_mfma_f32_16x16x32_bf16(a1, b0, acc[1][0], 0, 0, 0);
            acc[1][1] = __builtin_amdgcn_mfma_f32_16x16x32_bf16(a1, b1, acc[1][1], 0, 0, 0);
            acc[1][2] = __builtin_amdgcn_mfma_f32_16x16x32_bf16(a1, b2, acc[1][2], 0, 0, 0);
            acc[1][3] = __builtin_amdgcn_mfma_f32_16x16x32_bf16(a1, b3, acc[1][3], 0, 0, 0);
            acc[2][0] = __builtin_amdgcn_mfma_f32_16x16x32_bf16(a2, b0, acc[2][0], 0, 0, 0);
            acc[2][1] = __builtin_amdgcn_mfma_f32_16x16x32_bf16(a2, b1, acc[2][1], 0, 0, 0);
            acc[2][2] = __builtin_amdgcn_mfma_f32_16x16x32_bf16(a2, b2, acc[2][2], 0, 0, 0);
            acc[2][3] = __builtin_amdgcn_mfma_f32_16x16x32_bf16(a2, b3, acc[2][3], 0, 0, 0);
        }
    }

    // epilogue: BN (fp32) + GELU + fp32 residual from global, in-place write.
    // C/D layout: col(n) = lane&15, row(m) = quad*4 + reg  [measured m89/m91]
    #pragma unroll
    for (int mt = 0; mt < 3; mt++) {
        #pragma unroll
        for (int r = 0; r < 4; r++) {
            int oc = wid * 48 + mt * 16 + quad * 4 + r;
            float inv = pg[g * 192 + oc] * rsqrtf(pv[g * 192 + oc] + EPSBN);
            float bet = pb[g * 192 + oc] - pm[g * 192 + oc] * inv;
            #pragma unroll
            for (int nt = 0; nt < 4; nt++) {
                int p = nt * 16 + l15;
                if (p < 49) {
                    int y = p / 7, xx = p % 7;
                    long idx = ((long)oc * W + (Y0 + y)) * W + (X0 + xx);
                    float res = inb[idx];
                    inb[idx] = gelu_f(acc[mt][nt][r] * inv + bet) + res;
                }
            }
        }
    }
}

// ---------------- scalar fallback region conv (known-good), IN-PLACE ----------------
__global__ __launch_bounds__(192) void region_k(
        float* __restrict__ buf, const float* __restrict__ w,
        const float* __restrict__ pg, const float* __restrict__ pb,
        const float* __restrict__ pm, const float* __restrict__ pv,
        int B, int gw, int W) {
    __shared__ float tile[192 * 52];
    int bid = blockIdx.x;
    int b = bid % B;
    int g = bid / B;
    int gy = g / gw, gx = g % gw;
    int Y0 = gy * 7, X0 = gx * 7;
    const int tid = threadIdx.x;
    float* inb = buf + (long)b * 192 * W * W;
    for (int i = tid; i < 192 * 49; i += 192) {
        int ic = i / 49, p = i % 49;
        int y = p / 7, xx = p % 7;
        tile[ic * 52 + p] = inb[((long)ic * W + (Y0 + y)) * W + (X0 + xx)];
    }
    __syncthreads();
    const int oc = tid;
    float acc[49];
    #pragma unroll
    for (int i = 0; i < 49; i++) acc[i] = 0.f;
    const float* wbD = w + (((long)g * 192 + oc) * 192) * 9;
    for (int ic = 0; ic < 192; ic++) {
        float p[49];
        #pragma unroll
        for (int j = 0; j < 49; j++) p[j] = tile[ic * 52 + j];
        float wv[9];
        #pragma unroll
        for (int k = 0; k < 9; k++) wv[k] = wbD[(long)ic * 9 + k];
        #pragma unroll
        for (int ky = 0; ky < 3; ky++) {
            #pragma unroll
            for (int kx = 0; kx < 3; kx++) {
                float wk = wv[ky * 3 + kx];
                #pragma unroll
                for (int y = 0; y < 7; y++) {
                    int iy = y + ky - 1;
                    if (iy < 0 || iy >= 7) continue;
                    #pragma unroll
                    for (int xx = 0; xx < 7; xx++) {
                        int ix = xx + kx - 1;
                        if (ix < 0 || ix >= 7) continue;
                        acc[y * 7 + xx] += wk * p[iy * 7 + ix];
                    }
                }
            }
        }
    }
    float inv = pg[g * 192 + oc] * rsqrtf(pv[g * 192 + oc] + EPSBN);
    float bet = pb[g * 192 + oc] - pm[g * 192 + oc] * inv;
    float* ob = inb + (long)oc * W * W;
    #pragma unroll
    for (int pp = 0; pp < 49; pp++) {
        float val = gelu_f(acc[pp] * inv + bet) + tile[oc * 52 + pp];
        ob[((long)(Y0 + pp / 7)) * W + (X0 + pp % 7)] = val;
    }
}

// ---------------- conv2: 192->192, 2x2 stride 2, BN+GELU ----------------
__global__ __launch_bounds__(192) void conv2_k(
        const float* __restrict__ in, const float* __restrict__ wt,
        const float* __restrict__ bg, const float* __restrict__ bb,
        const float* __restrict__ bm, const float* __restrict__ bv,
        float* __restrict__ out) {
    int bid = blockIdx.x;
    int oy = bid % 28, b = bid / 28;
    int oc = threadIdx.x;
    float acc[28];
    #pragma unroll
    for (int i = 0; i < 28; i++) acc[i] = 0.f;
    for (int ic = 0; ic < 192; ic++) {
        #pragma unroll
        for (int ky = 0; ky < 2; ky++) {
            const float* row = in + (((long)b * 192 + ic) * 56 + (2 * oy + ky)) * 56;
            float w0 = wt[((ic * 2 + ky) * 2 + 0) * 192 + oc];
            float w1 = wt[((ic * 2 + ky) * 2 + 1) * 192 + oc];
            #pragma unroll
            for (int ox = 0; ox < 28; ox++) {
                float2 iv = *(const float2*)(row + 2 * ox);
                acc[ox] += iv.x * w0 + iv.y * w1;
            }
        }
    }
    float inv = bg[oc] * rsqrtf(bv[oc] + EPSBN);
    float bet = bb[oc] - bm[oc] * inv;
    float* ob = out + (((long)b * 192 + oc) * 28 + oy) * 28;
    #pragma unroll
    for (int ox = 0; ox < 28; ox++) ob[ox] = gelu_f(acc[ox] * inv + bet);
}

// ---------------- conv3: 192->768, 2x2 stride 2, BN, fused transpose store ----------------
__global__ __launch_bounds__(256) void conv3_k(
        const float* __restrict__ in, const float* __restrict__ wt,
        const float* __restrict__ bg, const float* __restrict__ bb,
        const float* __restrict__ bm, const float* __restrict__ bv,
        float* __restrict__ out) {
    int bid = blockIdx.x;
    int chunk = bid % 3; int t = bid / 3;
    int y = t % 14; int b = t / 14;
    int oc = chunk * 256 + threadIdx.x;
    float acc[14];
    #pragma unroll
    for (int i = 0; i < 14; i++) acc[i] = 0.f;
    for (int ic = 0; ic < 192; ic++) {
        #pragma unroll
        for (int ky = 0; ky < 2; ky++) {
            const float* row = in + (((long)b * 192 + ic) * 28 + (2 * y + ky)) * 28;
            float w0 = wt[((ic * 2 + ky) * 2 + 0) * 768 + oc];
            float w1 = wt[((ic * 2 + ky) * 2 + 1) * 768 + oc];
            #pragma unroll
            for (int xx = 0; xx < 14; xx++) {
                float2 iv = *(const float2*)(row + 2 * xx);
                acc[xx] += iv.x * w0 + iv.y * w1;
            }
        }
    }
    float inv = bg[oc] * rsqrtf(bv[oc] + EPSBN);
    float bet = bb[oc] - bm[oc] * inv;
    #pragma unroll
    for (int xx = 0; xx < 14; xx++)
        out[((long)b * 196 + y * 14 + xx) * 768 + oc] = acc[xx] * inv + bet;
}

extern "C" void kernel_launch(void* const* d_in, const int* in_sizes, int n_in,
                              void* d_out, int out_size, void* d_ws, size_t ws_size,
                              hipStream_t stream) {
    const float* x   = (const float*)d_in[0];
    const float* w1  = (const float*)d_in[1];
    const float* b1g = (const float*)d_in[2];
    const float* b1b = (const float*)d_in[3];
    const float* b1m = (const float*)d_in[4];
    const float* b1v = (const float*)d_in[5];
    const float* r1w = (const float*)d_in[6];
    const float* r1g = (const float*)d_in[7];
    const float* r1b = (const float*)d_in[8];
    const float* r1m = (const float*)d_in[9];
    const float* r1v = (const float*)d_in[10];
    const float* w2  = (const float*)d_in[11];
    const float* b2g = (const float*)d_in[12];
    const float* b2b = (const float*)d_in[13];
    const float* b2m = (const float*)d_in[14];
    const float* b2v = (const float*)d_in[15];
    const float* r2w = (const float*)d_in[16];
    const float* r2g = (const float*)d_in[17];
    const float* r2b = (const float*)d_in[18];
    const float* r2m = (const float*)d_in[19];
    const float* r2v = (const float*)d_in[20];
    const float* w3  = (const float*)d_in[21];
    const float* b3g = (const float*)d_in[22];
    const float* b3b = (const float*)d_in[23];
    const float* b3m = (const float*)d_in[24];
    const float* b3v = (const float*)d_in[25];
    float* out = (float*)d_out;

    char* ws = (char*)d_ws;
    const size_t SZ_H1   = 154140672UL;  // 64*192*56*56*4
    const size_t SZ_H2   = 38535168UL;   // 64*192*28*28*4
    const size_t SZ_CWT2 = 589824UL;     // 192*192*4*4
    const size_t SZ_CWT3 = 2359296UL;    // 768*192*4*4
    const size_t SZ_WB1  = 42467328UL;   // 64*192*9*192*2 (bf16)
    const size_t SZ_WB2  = 10616832UL;   // 16*192*9*192*2 (bf16)

    float* h1   = (float*)(ws);
    float* h2   = (float*)(ws + SZ_H1);
    float* cwt2 = (float*)(ws + SZ_H1 + SZ_H2);
    float* cwt3 = (float*)(ws + SZ_H1 + SZ_H2 + SZ_CWT2);
    size_t base = SZ_H1 + SZ_H2 + SZ_CWT2 + SZ_CWT3;
    unsigned short* wb1 = (unsigned short*)(ws + base);
    unsigned short* wb2 = (unsigned short*)(ws + base + SZ_WB1);
    int use_mfma = (ws_size >= base + SZ_WB1 + SZ_WB2) ? 1 : 0;

    wprep_small_k<<<576, 256, 0, stream>>>(w2, cwt2, 192, 192, 4);
    wprep_small_k<<<2304, 256, 0, stream>>>(w3, cwt3, 768, 192, 4);
    if (use_mfma) {
        wprep_bf16_k<<<8192, 256, 0, stream>>>(r1w, wb1, (long)64 * 192 * 9 * 192);
        wprep_bf16_k<<<2048, 256, 0, stream>>>(r2w, wb2, (long)16 * 192 * 9 * 192);
    }

    conv1_k<<<150528, 256, 0, stream>>>(x, w1, b1g, b1b, b1m, b1v, h1);
    if (use_mfma) {
        region_mfma_k<<<64 * 64, 256, 0, stream>>>(h1, wb1, r1g, r1b, r1m, r1v, 64, 8, 56);
    } else {
        region_k<<<64 * 64, 192, 0, stream>>>(h1, r1w, r1g, r1b, r1m, r1v, 64, 8, 56);
    }
    conv2_k<<<64 * 28, 192, 0, stream>>>(h1, cwt2, b2g, b2b, b2m, b2v, h2);
    if (use_mfma) {
        region_mfma_k<<<16 * 64, 256, 0, stream>>>(h2, wb2, r2g, r2b, r2m, r2v, 64, 4, 28);
    } else {
        region_k<<<16 * 64, 192, 0, stream>>>(h2, r2w, r2g, r2b, r2m, r2v, 64, 4, 28);
    }
    conv3_k<<<64 * 14 * 3, 256, 0, stream>>>(h2, cwt3, b3g, b3b, b3m, b3v, out);
}

// Round 4
// 1038.075 us; speedup vs baseline: 4.3272x; 2.1800x over previous
//
#include <hip/hip_runtime.h>
#include <hip/hip_bf16.h>
#include <math.h>

#define EPSBN 1e-5f

typedef short short8 __attribute__((ext_vector_type(8)));
typedef short short4v __attribute__((ext_vector_type(4)));
typedef float floatx4 __attribute__((ext_vector_type(4)));

__device__ __forceinline__ float gelu_f(float x) {
    return 0.5f * x * (1.0f + erff(x * 0.70710678118654752f));
}

__device__ __forceinline__ unsigned short f2bf(float f) {
    union { float f; unsigned int u; } c; c.f = f;
    unsigned int u = c.u;
    unsigned int r = (u + 0x7FFFu + ((u >> 16) & 1u)) >> 16;   // RNE
    return (unsigned short)r;
}

__device__ __forceinline__ float bf2f(unsigned short h) {
    union { unsigned int u; float f; } c; c.u = ((unsigned int)h) << 16;
    return c.f;
}

// ---------------- weight preps ----------------
// region weights: [G][oc][ic][3][3] fp32 -> [G][oc][t][ic] bf16
__global__ void wprep_bf16_k(const float* __restrict__ w, unsigned short* __restrict__ wb,
                             long total) {
    for (long o = (long)blockIdx.x * blockDim.x + threadIdx.x; o < total;
         o += (long)gridDim.x * blockDim.x) {
        int ic = (int)(o % 192); long t0 = o / 192;
        int t = (int)(t0 % 9); long t1 = t0 / 9;
        int oc = (int)(t1 % 192); long g = t1 / 192;
        wb[o] = f2bf(w[(((size_t)g * 192 + oc) * 192 + ic) * 9 + t]);
    }
}

// downsample weights: [OC][192][2][2] fp32 -> [t4][OC][192] bf16
__global__ void wprep_tap_k(const float* __restrict__ w, unsigned short* __restrict__ wb,
                            int OC) {
    long total = (long)4 * OC * 192;
    for (long o = (long)blockIdx.x * blockDim.x + threadIdx.x; o < total;
         o += (long)gridDim.x * blockDim.x) {
        int ic = (int)(o % 192); long t0 = o / 192;
        int oc = (int)(t0 % OC); int t = (int)(t0 / OC);
        wb[o] = f2bf(w[((size_t)oc * 192 + ic) * 4 + t]);
    }
}

// conv1 weights: [192][48] -> [48][192] fp32
__global__ void wprep_wt1_k(const float* __restrict__ w, float* __restrict__ wt) {
    int o = blockIdx.x * 256 + threadIdx.x;
    if (o < 9216) {
        int oc = o % 192, k = o / 192;
        wt[o] = w[oc * 48 + k];
    }
}

// ---------------- conv1: 3->192, 4x4 stride 4, BN+GELU, NHWC bf16 out ----------------
// block=(b,oy), 192 threads = oc
__global__ __launch_bounds__(192) void conv1_k(
        const float* __restrict__ x, const float* __restrict__ wt1,
        const float* __restrict__ bg, const float* __restrict__ bb,
        const float* __restrict__ bm, const float* __restrict__ bv,
        unsigned short* __restrict__ h1c) {
    __shared__ float xs[3][4][224];
    int b = blockIdx.x / 56, oy = blockIdx.x % 56;
    int tid = threadIdx.x;
    for (int i = tid; i < 2688; i += 192) {
        int col = i % 224, r = (i / 224) % 4, c = i / 896;
        xs[c][r][col] = x[(((size_t)b * 3 + c) * 224 + 4 * oy + r) * 224 + col];
    }
    float w[48];
    #pragma unroll
    for (int k = 0; k < 48; k++) w[k] = wt1[k * 192 + tid];
    float inv = bg[tid] * rsqrtf(bv[tid] + EPSBN);
    float bet = bb[tid] - bm[tid] * inv;
    __syncthreads();
    for (int ox = 0; ox < 56; ox++) {
        float a = 0.f;
        #pragma unroll
        for (int c = 0; c < 3; c++) {
            #pragma unroll
            for (int ky = 0; ky < 4; ky++) {
                float4 v = *(const float4*)&xs[c][ky][4 * ox];
                const float* wk = &w[(c * 4 + ky) * 4];
                a += v.x * wk[0] + v.y * wk[1] + v.z * wk[2] + v.w * wk[3];
            }
        }
        h1c[(((size_t)b * 56 + oy) * 56 + ox) * 192 + tid] = f2bf(gelu_f(a * inv + bet));
    }
}

// ---------------- region conv via MFMA, NHWC, A=pixels B=weights ----------------
// block = g*B + b; 256 thr = 4 waves (waves split oc: 48 each).
// INF32=0: in bf16 NHWC, in-place, residual from LDS tile.
// INF32=1: in fp32 NHWC, out separate bf16 NHWC, residual from global fp32.
#define TSTRIDE 232
template<int INF32>
__global__ __launch_bounds__(256) void region_mfma_k(
        const void* __restrict__ inbuf, void* __restrict__ outbuf,
        const unsigned short* __restrict__ wb,
        const float* __restrict__ pg, const float* __restrict__ pb,
        const float* __restrict__ pm, const float* __restrict__ pv,
        int B, int gw, int W) {
    __shared__ unsigned short lds[9 * 9 * TSTRIDE];
    const int bid = blockIdx.x;
    const int b = bid % B;
    const int g = bid / B;
    const int gy = g / gw, gx = g % gw;
    const int Y0 = gy * 7, X0 = gx * 7;
    const int tid = threadIdx.x;
    const int lane = tid & 63;
    const int wid = tid >> 6;
    const int quad = lane >> 4;
    const int l15 = lane & 15;
    const size_t slab = (size_t)b * W * W * 192;
    const unsigned short* in_u16 = (const unsigned short*)inbuf + slab;
    const float* in_f32 = (const float*)inbuf + slab;
    unsigned short* outb = (unsigned short*)outbuf + slab;

    // zero LDS, then fill interior from NHWC (ic-contiguous: coalesced)
    {
        short8* z = (short8*)lds;
        short8 zv = (short8)0;
        for (int i = tid; i < (9 * 9 * TSTRIDE) / 8; i += 256) z[i] = zv;
    }
    __syncthreads();
    for (int i = tid; i < 49 * 192; i += 256) {
        int ic = i % 192, p = i / 192;
        int y = p / 7, xx = p % 7;
        size_t src = ((size_t)(Y0 + y) * W + (X0 + xx)) * 192 + ic;
        unsigned short v = INF32 ? f2bf(in_f32[src]) : in_u16[src];
        lds[((y + 1) * 9 + (xx + 1)) * TSTRIDE + ic] = v;
    }
    __syncthreads();

    // A(pixel) m-tiles: pixel = mt*16 + l15 (clamped; invalid rows discarded at store)
    int py[4], px[4];
    #pragma unroll
    for (int mt = 0; mt < 4; mt++) {
        int p = mt * 16 + l15; if (p > 48) p = 48;
        py[mt] = p / 7; px[mt] = p % 7;
    }
    // B(weight) base ptrs: oc = wid*48 + nt*16 + l15
    const unsigned short* baseW[3];
    #pragma unroll
    for (int nt = 0; nt < 3; nt++) {
        int oc = wid * 48 + nt * 16 + l15;
        baseW[nt] = wb + ((size_t)(g * 192 + oc)) * 9 * 192;
    }

    floatx4 acc[4][3];
    #pragma unroll
    for (int mt = 0; mt < 4; mt++)
        #pragma unroll
        for (int nt = 0; nt < 3; nt++) acc[mt][nt] = (floatx4)0.f;

    for (int t = 0; t < 9; t++) {
        const int ky = t / 3, kx = t % 3;
        int cellb[4];
        #pragma unroll
        for (int mt = 0; mt < 4; mt++)
            cellb[mt] = ((py[mt] + ky) * 9 + (px[mt] + kx)) * TSTRIDE;
        const unsigned short* wt0 = baseW[0] + t * 192;
        const unsigned short* wt1 = baseW[1] + t * 192;
        const unsigned short* wt2 = baseW[2] + t * 192;
        #pragma unroll
        for (int s = 0; s < 6; s++) {
            const int ic0 = s * 32 + quad * 8;
            short8 w0 = *(const short8*)(wt0 + ic0);
            short8 w1 = *(const short8*)(wt1 + ic0);
            short8 w2 = *(const short8*)(wt2 + ic0);
            short8 p0 = *(const short8*)(&lds[cellb[0] + ic0]);
            short8 p1 = *(const short8*)(&lds[cellb[1] + ic0]);
            short8 p2 = *(const short8*)(&lds[cellb[2] + ic0]);
            short8 p3 = *(const short8*)(&lds[cellb[3] + ic0]);
            acc[0][0] = __builtin_amdgcn_mfma_f32_16x16x32_bf16(p0, w0, acc[0][0], 0, 0, 0);
            acc[0][1] = __builtin_amdgcn_mfma_f32_16x16x32_bf16(p0, w1, acc[0][1], 0, 0, 0);
            acc[0][2] = __builtin_amdgcn_mfma_f32_16x16x32_bf16(p0, w2, acc[0][2], 0, 0, 0);
            acc[1][0] = __builtin_amdgcn_mfma_f32_16x16x32_bf16(p1, w0, acc[1][0], 0, 0, 0);
            acc[1][1] = __builtin_amdgcn_mfma_f32_16x16x32_bf16(p1, w1, acc[1][1], 0, 0, 0);
            acc[1][2] = __builtin_amdgcn_mfma_f32_16x16x32_bf16(p1, w2, acc[1][2], 0, 0, 0);
            acc[2][0] = __builtin_amdgcn_mfma_f32_16x16x32_bf16(p2, w0, acc[2][0], 0, 0, 0);
            acc[2][1] = __builtin_amdgcn_mfma_f32_16x16x32_bf16(p2, w1, acc[2][1], 0, 0, 0);
            acc[2][2] = __builtin_amdgcn_mfma_f32_16x16x32_bf16(p2, w2, acc[2][2], 0, 0, 0);
            acc[3][0] = __builtin_amdgcn_mfma_f32_16x16x32_bf16(p3, w0, acc[3][0], 0, 0, 0);
            acc[3][1] = __builtin_amdgcn_mfma_f32_16x16x32_bf16(p3, w1, acc[3][1], 0, 0, 0);
            acc[3][2] = __builtin_amdgcn_mfma_f32_16x16x32_bf16(p3, w2, acc[3][2], 0, 0, 0);
        }
    }

    // epilogue: C row = pixel (quad*4+r within m-tile), col = oc (l15). NHWC store.
    #pragma unroll
    for (int nt = 0; nt < 3; nt++) {
        int oc = wid * 48 + nt * 16 + l15;
        float inv = pg[g * 192 + oc] * rsqrtf(pv[g * 192 + oc] + EPSBN);
        float bet = pb[g * 192 + oc] - pm[g * 192 + oc] * inv;
        #pragma unroll
        for (int mt = 0; mt < 4; mt++) {
            #pragma unroll
            for (int r = 0; r < 4; r++) {
                int p = mt * 16 + quad * 4 + r;
                if (p < 49) {
                    int y = p / 7, xx = p % 7;
                    size_t pix = (size_t)(Y0 + y) * W + (X0 + xx);
                    float res;
                    if (INF32) res = in_f32[pix * 192 + oc];
                    else       res = bf2f(lds[((y + 1) * 9 + (xx + 1)) * TSTRIDE + oc]);
                    float val = gelu_f(acc[mt][nt][r] * inv + bet) + res;
                    outb[pix * 192 + oc] = f2bf(val);
                }
            }
        }
    }
}

// ---------------- conv2 via MFMA: 192->192, 2x2 s2, BN+GELU, bf16NHWC -> fp32NHWC ----------
// block=(b, oy-chunk of 4): M=112 px (7 m-tiles), waves split oc 4x48 (3 n-tiles). K=768.
__global__ __launch_bounds__(256) void conv2_mfma_k(
        const unsigned short* __restrict__ h1c, const unsigned short* __restrict__ wb,
        const float* __restrict__ bg, const float* __restrict__ bb,
        const float* __restrict__ bm, const float* __restrict__ bv,
        float* __restrict__ h2c) {
    __shared__ unsigned short lds[2 * 112 * 40];
    const int b = blockIdx.x / 7;
    const int oy0 = (blockIdx.x % 7) * 4;
    const int tid = threadIdx.x;
    const int lane = tid & 63;
    const int wid = tid >> 6;
    const int quad = lane >> 4;
    const int l15 = lane & 15;

    floatx4 acc[7][3];
    #pragma unroll
    for (int mt = 0; mt < 7; mt++)
        #pragma unroll
        for (int nt = 0; nt < 3; nt++) acc[mt][nt] = (floatx4)0.f;

    for (int ky = 0; ky < 2; ky++) {
        for (int c = 0; c < 6; c++) {
            __syncthreads();
            // stage both kx taps for ic-chunk c: [kx][p][ic0..31], short4 per thread
            for (int i = tid; i < 1792; i += 256) {
                int icq = i & 7, kx = (i >> 3) & 1, p = i >> 4;
                int oy = oy0 + p / 28, ox = p % 28;
                int iy = 2 * oy + ky, ix = 2 * ox + kx;
                const unsigned short* src =
                    h1c + (((size_t)b * 56 + iy) * 56 + ix) * 192 + c * 32 + icq * 4;
                *(short4v*)(&lds[kx * 4480 + p * 40 + icq * 4]) = *(const short4v*)src;
            }
            __syncthreads();
            #pragma unroll
            for (int kx = 0; kx < 2; kx++) {
                const int t = ky * 2 + kx;
                short8 wf[3];
                #pragma unroll
                for (int nt = 0; nt < 3; nt++) {
                    int oc = wid * 48 + nt * 16 + l15;
                    wf[nt] = *(const short8*)(wb + ((size_t)(t * 192 + oc)) * 192 + c * 32 + quad * 8);
                }
                #pragma unroll
                for (int mt = 0; mt < 7; mt++) {
                    short8 ap = *(const short8*)(&lds[kx * 4480 + (mt * 16 + l15) * 40 + quad * 8]);
                    #pragma unroll
                    for (int nt = 0; nt < 3; nt++)
                        acc[mt][nt] = __builtin_amdgcn_mfma_f32_16x16x32_bf16(ap, wf[nt], acc[mt][nt], 0, 0, 0);
                }
            }
        }
    }
    #pragma unroll
    for (int nt = 0; nt < 3; nt++) {
        int oc = wid * 48 + nt * 16 + l15;
        float inv = bg[oc] * rsqrtf(bv[oc] + EPSBN);
        float bet = bb[oc] - bm[oc] * inv;
        #pragma unroll
        for (int mt = 0; mt < 7; mt++) {
            #pragma unroll
            for (int r = 0; r < 4; r++) {
                int p = mt * 16 + quad * 4 + r;
                int oy = oy0 + p / 28, ox = p % 28;
                h2c[(((size_t)b * 28 + oy) * 28 + ox) * 192 + oc] = gelu_f(acc[mt][nt][r] * inv + bet);
            }
        }
    }
}

// ---------------- conv3 via MFMA: 192->768, 2x2 s2, BN, fp... bf16NHWC -> out (B,196,768) ----
// block=(b, s2, octile3): M=98 px (7 m-tiles, clamp), N=256 oc (waves split 4x64 -> 4 n-tiles).
__global__ __launch_bounds__(256) void conv3_mfma_k(
        const unsigned short* __restrict__ h2b, const unsigned short* __restrict__ wb,
        const float* __restrict__ bg, const float* __restrict__ bb,
        const float* __restrict__ bm, const float* __restrict__ bv,
        float* __restrict__ out) {
    __shared__ unsigned short lds[2 * 112 * 40];
    const int bid = blockIdx.x;
    const int b = bid / 6;
    const int s = (bid % 6) / 3;
    const int octile = bid % 3;
    const int y0 = s * 7;
    const int tid = threadIdx.x;
    const int lane = tid & 63;
    const int wid = tid >> 6;
    const int quad = lane >> 4;
    const int l15 = lane & 15;

    floatx4 acc[7][4];
    #pragma unroll
    for (int mt = 0; mt < 7; mt++)
        #pragma unroll
        for (int nt = 0; nt < 4; nt++) acc[mt][nt] = (floatx4)0.f;

    for (int ky = 0; ky < 2; ky++) {
        for (int c = 0; c < 6; c++) {
            __syncthreads();
            for (int i = tid; i < 1568; i += 256) {   // 98 px * 2 kx * 8 short4
                int icq = i & 7, kx = (i >> 3) & 1, p = i >> 4;
                int oy = y0 + p / 14, ox = p % 14;
                int iy = 2 * oy + ky, ix = 2 * ox + kx;
                const unsigned short* src =
                    h2b + (((size_t)b * 28 + iy) * 28 + ix) * 192 + c * 32 + icq * 4;
                *(short4v*)(&lds[kx * 4480 + p * 40 + icq * 4]) = *(const short4v*)src;
            }
            __syncthreads();
            #pragma unroll
            for (int kx = 0; kx < 2; kx++) {
                const int t = ky * 2 + kx;
                short8 wf[4];
                #pragma unroll
                for (int nt = 0; nt < 4; nt++) {
                    int oc = octile * 256 + wid * 64 + nt * 16 + l15;
                    wf[nt] = *(const short8*)(wb + ((size_t)(t * 768 + oc)) * 192 + c * 32 + quad * 8);
                }
                #pragma unroll
                for (int mt = 0; mt < 7; mt++) {
                    int p = mt * 16 + l15; if (p > 97) p = 97;
                    short8 ap = *(const short8*)(&lds[kx * 4480 + p * 40 + quad * 8]);
                    #pragma unroll
                    for (int nt = 0; nt < 4; nt++)
                        acc[mt][nt] = __builtin_amdgcn_mfma_f32_16x16x32_bf16(ap, wf[nt], acc[mt][nt], 0, 0, 0);
                }
            }
        }
    }
    #pragma unroll
    for (int nt = 0; nt < 4; nt++) {
        int oc = octile * 256 + wid * 64 + nt * 16 + l15;
        float inv = bg[oc] * rsqrtf(bv[oc] + EPSBN);
        float bet = bb[oc] - bm[oc] * inv;
        #pragma unroll
        for (int mt = 0; mt < 7; mt++) {
            #pragma unroll
            for (int r = 0; r < 4; r++) {
                int p = mt * 16 + quad * 4 + r;
                if (p < 98) {
                    int oy = y0 + p / 14, ox = p % 14;
                    out[((size_t)b * 196 + oy * 14 + ox) * 768 + oc] = acc[mt][nt][r] * inv + bet;
                }
            }
        }
    }
}

extern "C" void kernel_launch(void* const* d_in, const int* in_sizes, int n_in,
                              void* d_out, int out_size, void* d_ws, size_t ws_size,
                              hipStream_t stream) {
    const float* x   = (const float*)d_in[0];
    const float* w1  = (const float*)d_in[1];
    const float* b1g = (const float*)d_in[2];
    const float* b1b = (const float*)d_in[3];
    const float* b1m = (const float*)d_in[4];
    const float* b1v = (const float*)d_in[5];
    const float* r1w = (const float*)d_in[6];
    const float* r1g = (const float*)d_in[7];
    const float* r1b = (const float*)d_in[8];
    const float* r1m = (const float*)d_in[9];
    const float* r1v = (const float*)d_in[10];
    const float* w2  = (const float*)d_in[11];
    const float* b2g = (const float*)d_in[12];
    const float* b2b = (const float*)d_in[13];
    const float* b2m = (const float*)d_in[14];
    const float* b2v = (const float*)d_in[15];
    const float* r2w = (const float*)d_in[16];
    const float* r2g = (const float*)d_in[17];
    const float* r2b = (const float*)d_in[18];
    const float* r2m = (const float*)d_in[19];
    const float* r2v = (const float*)d_in[20];
    const float* w3  = (const float*)d_in[21];
    const float* b3g = (const float*)d_in[22];
    const float* b3b = (const float*)d_in[23];
    const float* b3m = (const float*)d_in[24];
    const float* b3v = (const float*)d_in[25];
    float* out = (float*)d_out;

    char* ws = (char*)d_ws;
    // layout (bytes):                         offset        size
    unsigned short* h1c  = (unsigned short*)(ws + 0);            // 77,070,336  bf16 NHWC 56x56 (in-place region1)
    float*          h2c  = (float*)         (ws + 77070336UL);   // 38,535,168  fp32 NHWC 28x28
    unsigned short* h2b  = (unsigned short*)(ws + 115605504UL);  // 19,267,584  bf16 NHWC 28x28
    unsigned short* wb1  = (unsigned short*)(ws + 134873088UL);  // 42,467,328
    unsigned short* wb2r = (unsigned short*)(ws + 177340416UL);  // 10,616,832
    float*          wt1  = (float*)         (ws + 187957248UL);  //     36,864
    unsigned short* wb2c = (unsigned short*)(ws + 187994112UL);  //    294,912
    unsigned short* wb3c = (unsigned short*)(ws + 188289024UL);  //  1,179,648
    // total 189,468,672 B (< 249 MB proven available in R3)

    wprep_bf16_k<<<8192, 256, 0, stream>>>(r1w, wb1, (long)64 * 192 * 9 * 192);
    wprep_bf16_k<<<2048, 256, 0, stream>>>(r2w, wb2r, (long)16 * 192 * 9 * 192);
    wprep_tap_k<<<576, 256, 0, stream>>>(w2, wb2c, 192);
    wprep_tap_k<<<2304, 256, 0, stream>>>(w3, wb3c, 768);
    wprep_wt1_k<<<36, 256, 0, stream>>>(w1, wt1);

    conv1_k<<<64 * 56, 192, 0, stream>>>(x, wt1, b1g, b1b, b1m, b1v, h1c);
    region_mfma_k<0><<<64 * 64, 256, 0, stream>>>(h1c, h1c, wb1, r1g, r1b, r1m, r1v, 64, 8, 56);
    conv2_mfma_k<<<64 * 7, 256, 0, stream>>>(h1c, wb2c, b2g, b2b, b2m, b2v, h2c);
    region_mfma_k<1><<<16 * 64, 256, 0, stream>>>(h2c, h2b, wb2r, r2g, r2b, r2m, r2v, 64, 4, 28);
    conv3_mfma_k<<<64 * 6, 256, 0, stream>>>(h2b, wb3c, b3g, b3b, b3m, b3v, out);
}

// Round 5
// 986.808 us; speedup vs baseline: 4.5521x; 1.0520x over previous
//
#include <hip/hip_runtime.h>
#include <hip/hip_bf16.h>
#include <math.h>

#define EPSBN 1e-5f

typedef short short8 __attribute__((ext_vector_type(8)));
typedef short short4v __attribute__((ext_vector_type(4)));
typedef float floatx4 __attribute__((ext_vector_type(4)));

__device__ __forceinline__ float gelu_f(float x) {
    return 0.5f * x * (1.0f + erff(x * 0.70710678118654752f));
}

__device__ __forceinline__ unsigned short f2bf(float f) {
    union { float f; unsigned int u; } c; c.f = f;
    unsigned int u = c.u;
    unsigned int r = (u + 0x7FFFu + ((u >> 16) & 1u)) >> 16;   // RNE
    return (unsigned short)r;
}

__device__ __forceinline__ float bf2f(unsigned short h) {
    union { unsigned int u; float f; } c; c.u = ((unsigned int)h) << 16;
    return c.f;
}

// ---------------- weight preps ----------------
// region weights: [G][oc][ic][3][3] fp32 -> [G][oc][t][ic] bf16
__global__ void wprep_bf16_k(const float* __restrict__ w, unsigned short* __restrict__ wb,
                             long total) {
    for (long o = (long)blockIdx.x * blockDim.x + threadIdx.x; o < total;
         o += (long)gridDim.x * blockDim.x) {
        int ic = (int)(o % 192); long t0 = o / 192;
        int t = (int)(t0 % 9); long t1 = t0 / 9;
        int oc = (int)(t1 % 192); long g = t1 / 192;
        wb[o] = f2bf(w[(((size_t)g * 192 + oc) * 192 + ic) * 9 + t]);
    }
}

// downsample weights: [OC][192][2][2] fp32 -> [t4][OC][192] bf16
__global__ void wprep_tap_k(const float* __restrict__ w, unsigned short* __restrict__ wb,
                            int OC) {
    long total = (long)4 * OC * 192;
    for (long o = (long)blockIdx.x * blockDim.x + threadIdx.x; o < total;
         o += (long)gridDim.x * blockDim.x) {
        int ic = (int)(o % 192); long t0 = o / 192;
        int oc = (int)(t0 % OC); int t = (int)(t0 / OC);
        wb[o] = f2bf(w[((size_t)oc * 192 + ic) * 4 + t]);
    }
}

// conv1 weights: [192][48] -> [48][192] fp32
__global__ void wprep_wt1_k(const float* __restrict__ w, float* __restrict__ wt) {
    int o = blockIdx.x * 256 + threadIdx.x;
    if (o < 9216) {
        int oc = o % 192, k = o / 192;
        wt[o] = w[oc * 48 + k];
    }
}

// ---------------- conv1: 3->192, 4x4 stride 4, BN+GELU, NHWC bf16 out ----------------
__global__ __launch_bounds__(192) void conv1_k(
        const float* __restrict__ x, const float* __restrict__ wt1,
        const float* __restrict__ bg, const float* __restrict__ bb,
        const float* __restrict__ bm, const float* __restrict__ bv,
        unsigned short* __restrict__ h1c) {
    __shared__ float xs[3][4][224];
    int b = blockIdx.x / 56, oy = blockIdx.x % 56;
    int tid = threadIdx.x;
    for (int i = tid; i < 2688; i += 192) {
        int col = i % 224, r = (i / 224) % 4, c = i / 896;
        xs[c][r][col] = x[(((size_t)b * 3 + c) * 224 + 4 * oy + r) * 224 + col];
    }
    float w[48];
    #pragma unroll
    for (int k = 0; k < 48; k++) w[k] = wt1[k * 192 + tid];
    float inv = bg[tid] * rsqrtf(bv[tid] + EPSBN);
    float bet = bb[tid] - bm[tid] * inv;
    __syncthreads();
    for (int ox = 0; ox < 56; ox++) {
        float a = 0.f;
        #pragma unroll
        for (int c = 0; c < 3; c++) {
            #pragma unroll
            for (int ky = 0; ky < 4; ky++) {
                float4 v = *(const float4*)&xs[c][ky][4 * ox];
                const float* wk = &w[(c * 4 + ky) * 4];
                a += v.x * wk[0] + v.y * wk[1] + v.z * wk[2] + v.w * wk[3];
            }
        }
        h1c[(((size_t)b * 56 + oy) * 56 + ox) * 192 + tid] = f2bf(gelu_f(a * inv + bet));
    }
}

// ---------------- region conv via MFMA v2: 2 batches/block, wave = 64px x 96oc ----------
// grid = G*32; swizzle: XCD (bid&7) == g%8, b-pairs sequential per g -> weight slab
// stays L2-resident per XCD. LDS: 2 tiles, row stride 200 shorts (word-stride 100 ≡ 4
// mod 32 -> worst 2-way bank aliasing = free). Per K32 per wave: 4 LDS + 6 global b128
// reads feeding 24 MFMAs (LDS 170 B/MFMA, L1 256 B/MFMA - inside pipe budgets).
#define RST 200
#define TILE_SH (81 * RST)
template<int INF32>
__global__ __launch_bounds__(256, 2) void region_mfma2_k(
        const void* __restrict__ inbuf, void* __restrict__ outbuf,
        const unsigned short* __restrict__ wb,
        const float* __restrict__ pg, const float* __restrict__ pb,
        const float* __restrict__ pm, const float* __restrict__ pv,
        int gw, int W) {
    __shared__ unsigned short lds[2 * TILE_SH];   // 64800 B
    const int raw = blockIdx.x;
    const int g = (raw & 7) + 8 * (raw >> 8);     // raw>>8 == (raw>>3)/32
    const int bp = (raw >> 3) & 31;
    const int b0 = bp * 2;
    const int gy = g / gw, gx = g % gw;
    const int Y0 = gy * 7, X0 = gx * 7;
    const int tid = threadIdx.x;
    const int lane = tid & 63;
    const int wid = tid >> 6;
    const int quad = lane >> 4;
    const int l15 = lane & 15;

    const size_t slab0 = (size_t)b0 * W * W * 192;
    const size_t tsz = (size_t)W * W * 192;

    // halo zero (perimeter cells only), vectorized
    for (int i = tid; i < 1536; i += 256) {
        int tI = i / 768, rem = i % 768, h = rem / 24, ch = rem % 24;
        int cell;
        if (h < 9) cell = h;
        else if (h < 18) cell = 72 + (h - 9);
        else { int h2 = h - 18; cell = (1 + (h2 >> 1)) * 9 + ((h2 & 1) * 8); }
        *(short8*)&lds[tI * TILE_SH + cell * RST + ch * 8] = (short8)0;
    }
    // interior fill, b128 per lane
    for (int i = tid; i < 2352; i += 256) {
        int tI = i / 1176, rem = i % 1176, p = rem / 24, ch = rem % 24;
        int y = p / 7, xx = p % 7;
        size_t poff = slab0 + (size_t)tI * tsz + ((size_t)(Y0 + y) * W + (X0 + xx)) * 192 + ch * 8;
        short8 v;
        if (INF32) {
            const float* s4 = (const float*)inbuf + poff;
            float4 a = *(const float4*)s4;
            float4 b2 = *(const float4*)(s4 + 4);
            v[0] = (short)f2bf(a.x);  v[1] = (short)f2bf(a.y);
            v[2] = (short)f2bf(a.z);  v[3] = (short)f2bf(a.w);
            v[4] = (short)f2bf(b2.x); v[5] = (short)f2bf(b2.y);
            v[6] = (short)f2bf(b2.z); v[7] = (short)f2bf(b2.w);
        } else {
            v = *(const short8*)((const unsigned short*)inbuf + poff);
        }
        *(short8*)&lds[tI * TILE_SH + ((y + 1) * 9 + (xx + 1)) * RST + ch * 8] = v;
    }
    __syncthreads();

    const int tilebase = (wid >> 1) * TILE_SH;
    const int ocbase = (wid & 1) * 96;

    // per-lane invariants
    int pyv[4], pxv[4];
    #pragma unroll
    for (int mt = 0; mt < 4; mt++) {
        int p = mt * 16 + l15; if (p > 48) p = 48;
        pyv[mt] = p / 7; pxv[mt] = p % 7;
    }
    int woff[6];
    #pragma unroll
    for (int nt = 0; nt < 6; nt++)
        woff[nt] = (ocbase + nt * 16 + l15) * 1728 + quad * 8;
    const unsigned short* wbg = wb + (size_t)g * 331776;

    floatx4 acc[4][6];
    #pragma unroll
    for (int mt = 0; mt < 4; mt++)
        #pragma unroll
        for (int nt = 0; nt < 6; nt++) acc[mt][nt] = (floatx4)0.f;

    for (int t = 0; t < 9; t++) {
        const int ky = t / 3, kx = t % 3;
        int ca[4];
        #pragma unroll
        for (int mt = 0; mt < 4; mt++)
            ca[mt] = tilebase + ((pyv[mt] + ky) * 9 + (pxv[mt] + kx)) * RST + quad * 8;
        const int toff = t * 192;
        #pragma unroll
        for (int s = 0; s < 6; s++) {
            const int ic0 = s * 32;
            short8 pf[4];
            #pragma unroll
            for (int mt = 0; mt < 4; mt++)
                pf[mt] = *(const short8*)&lds[ca[mt] + ic0];
            short8 wf[6];
            #pragma unroll
            for (int nt = 0; nt < 6; nt++)
                wf[nt] = *(const short8*)(wbg + woff[nt] + toff + ic0);
            #pragma unroll
            for (int mt = 0; mt < 4; mt++)
                #pragma unroll
                for (int nt = 0; nt < 6; nt++)
                    acc[mt][nt] = __builtin_amdgcn_mfma_f32_16x16x32_bf16(pf[mt], wf[nt], acc[mt][nt], 0, 0, 0);
        }
    }

    // epilogue: C row = pixel (mt*16 + quad*4 + r), col = oc (l15). NHWC bf16 store.
    const size_t oslab = slab0 + (size_t)(wid >> 1) * tsz;
    unsigned short* outb = (unsigned short*)outbuf + oslab;
    const float* resf = (const float*)inbuf + oslab;
    #pragma unroll
    for (int nt = 0; nt < 6; nt++) {
        int oc = ocbase + nt * 16 + l15;
        float inv = pg[g * 192 + oc] * rsqrtf(pv[g * 192 + oc] + EPSBN);
        float bet = pb[g * 192 + oc] - pm[g * 192 + oc] * inv;
        #pragma unroll
        for (int mt = 0; mt < 4; mt++) {
            #pragma unroll
            for (int r = 0; r < 4; r++) {
                int p = mt * 16 + quad * 4 + r;
                if (p < 49) {
                    int y = p / 7, xx = p % 7;
                    size_t pix = (size_t)(Y0 + y) * W + (X0 + xx);
                    float res;
                    if (INF32) res = resf[pix * 192 + oc];
                    else       res = bf2f(lds[tilebase + ((y + 1) * 9 + (xx + 1)) * RST + oc]);
                    outb[pix * 192 + oc] = f2bf(gelu_f(acc[mt][nt][r] * inv + bet) + res);
                }
            }
        }
    }
}

// ---------------- conv2 via MFMA: 192->192, 2x2 s2, BN+GELU, bf16NHWC -> fp32NHWC ----------
__global__ __launch_bounds__(256) void conv2_mfma_k(
        const unsigned short* __restrict__ h1c, const unsigned short* __restrict__ wb,
        const float* __restrict__ bg, const float* __restrict__ bb,
        const float* __restrict__ bm, const float* __restrict__ bv,
        float* __restrict__ h2c) {
    __shared__ unsigned short lds[2 * 112 * 40];
    const int b = blockIdx.x / 7;
    const int oy0 = (blockIdx.x % 7) * 4;
    const int tid = threadIdx.x;
    const int lane = tid & 63;
    const int wid = tid >> 6;
    const int quad = lane >> 4;
    const int l15 = lane & 15;

    floatx4 acc[7][3];
    #pragma unroll
    for (int mt = 0; mt < 7; mt++)
        #pragma unroll
        for (int nt = 0; nt < 3; nt++) acc[mt][nt] = (floatx4)0.f;

    for (int ky = 0; ky < 2; ky++) {
        for (int c = 0; c < 6; c++) {
            __syncthreads();
            for (int i = tid; i < 1792; i += 256) {
                int icq = i & 7, kx = (i >> 3) & 1, p = i >> 4;
                int oy = oy0 + p / 28, ox = p % 28;
                int iy = 2 * oy + ky, ix = 2 * ox + kx;
                const unsigned short* src =
                    h1c + (((size_t)b * 56 + iy) * 56 + ix) * 192 + c * 32 + icq * 4;
                *(short4v*)(&lds[kx * 4480 + p * 40 + icq * 4]) = *(const short4v*)src;
            }
            __syncthreads();
            #pragma unroll
            for (int kx = 0; kx < 2; kx++) {
                const int t = ky * 2 + kx;
                short8 wf[3];
                #pragma unroll
                for (int nt = 0; nt < 3; nt++) {
                    int oc = wid * 48 + nt * 16 + l15;
                    wf[nt] = *(const short8*)(wb + ((size_t)(t * 192 + oc)) * 192 + c * 32 + quad * 8);
                }
                #pragma unroll
                for (int mt = 0; mt < 7; mt++) {
                    short8 ap = *(const short8*)(&lds[kx * 4480 + (mt * 16 + l15) * 40 + quad * 8]);
                    #pragma unroll
                    for (int nt = 0; nt < 3; nt++)
                        acc[mt][nt] = __builtin_amdgcn_mfma_f32_16x16x32_bf16(ap, wf[nt], acc[mt][nt], 0, 0, 0);
                }
            }
        }
    }
    #pragma unroll
    for (int nt = 0; nt < 3; nt++) {
        int oc = wid * 48 + nt * 16 + l15;
        float inv = bg[oc] * rsqrtf(bv[oc] + EPSBN);
        float bet = bb[oc] - bm[oc] * inv;
        #pragma unroll
        for (int mt = 0; mt < 7; mt++) {
            #pragma unroll
            for (int r = 0; r < 4; r++) {
                int p = mt * 16 + quad * 4 + r;
                int oy = oy0 + p / 28, ox = p % 28;
                h2c[(((size_t)b * 28 + oy) * 28 + ox) * 192 + oc] = gelu_f(acc[mt][nt][r] * inv + bet);
            }
        }
    }
}

// ---------------- conv3 via MFMA: 192->768, 2x2 s2, BN, bf16NHWC -> out (B,196,768) ----
__global__ __launch_bounds__(256) void conv3_mfma_k(
        const unsigned short* __restrict__ h2b, const unsigned short* __restrict__ wb,
        const float* __restrict__ bg, const float* __restrict__ bb,
        const float* __restrict__ bm, const float* __restrict__ bv,
        float* __restrict__ out) {
    __shared__ unsigned short lds[2 * 112 * 40];
    const int bid = blockIdx.x;
    const int b = bid / 6;
    const int s = (bid % 6) / 3;
    const int octile = bid % 3;
    const int y0 = s * 7;
    const int tid = threadIdx.x;
    const int lane = tid & 63;
    const int wid = tid >> 6;
    const int quad = lane >> 4;
    const int l15 = lane & 15;

    floatx4 acc[7][4];
    #pragma unroll
    for (int mt = 0; mt < 7; mt++)
        #pragma unroll
        for (int nt = 0; nt < 4; nt++) acc[mt][nt] = (floatx4)0.f;

    for (int ky = 0; ky < 2; ky++) {
        for (int c = 0; c < 6; c++) {
            __syncthreads();
            for (int i = tid; i < 1568; i += 256) {
                int icq = i & 7, kx = (i >> 3) & 1, p = i >> 4;
                int oy = y0 + p / 14, ox = p % 14;
                int iy = 2 * oy + ky, ix = 2 * ox + kx;
                const unsigned short* src =
                    h2b + (((size_t)b * 28 + iy) * 28 + ix) * 192 + c * 32 + icq * 4;
                *(short4v*)(&lds[kx * 4480 + p * 40 + icq * 4]) = *(const short4v*)src;
            }
            __syncthreads();
            #pragma unroll
            for (int kx = 0; kx < 2; kx++) {
                const int t = ky * 2 + kx;
                short8 wf[4];
                #pragma unroll
                for (int nt = 0; nt < 4; nt++) {
                    int oc = octile * 256 + wid * 64 + nt * 16 + l15;
                    wf[nt] = *(const short8*)(wb + ((size_t)(t * 768 + oc)) * 192 + c * 32 + quad * 8);
                }
                #pragma unroll
                for (int mt = 0; mt < 7; mt++) {
                    int p = mt * 16 + l15; if (p > 97) p = 97;
                    short8 ap = *(const short8*)(&lds[kx * 4480 + p * 40 + quad * 8]);
                    #pragma unroll
                    for (int nt = 0; nt < 4; nt++)
                        acc[mt][nt] = __builtin_amdgcn_mfma_f32_16x16x32_bf16(ap, wf[nt], acc[mt][nt], 0, 0, 0);
                }
            }
        }
    }
    #pragma unroll
    for (int nt = 0; nt < 4; nt++) {
        int oc = octile * 256 + wid * 64 + nt * 16 + l15;
        float inv = bg[oc] * rsqrtf(bv[oc] + EPSBN);
        float bet = bb[oc] - bm[oc] * inv;
        #pragma unroll
        for (int mt = 0; mt < 7; mt++) {
            #pragma unroll
            for (int r = 0; r < 4; r++) {
                int p = mt * 16 + quad * 4 + r;
                if (p < 98) {
                    int oy = y0 + p / 14, ox = p % 14;
                    out[((size_t)b * 196 + oy * 14 + ox) * 768 + oc] = acc[mt][nt][r] * inv + bet;
                }
            }
        }
    }
}

extern "C" void kernel_launch(void* const* d_in, const int* in_sizes, int n_in,
                              void* d_out, int out_size, void* d_ws, size_t ws_size,
                              hipStream_t stream) {
    const float* x   = (const float*)d_in[0];
    const float* w1  = (const float*)d_in[1];
    const float* b1g = (const float*)d_in[2];
    const float* b1b = (const float*)d_in[3];
    const float* b1m = (const float*)d_in[4];
    const float* b1v = (const float*)d_in[5];
    const float* r1w = (const float*)d_in[6];
    const float* r1g = (const float*)d_in[7];
    const float* r1b = (const float*)d_in[8];
    const float* r1m = (const float*)d_in[9];
    const float* r1v = (const float*)d_in[10];
    const float* w2  = (const float*)d_in[11];
    const float* b2g = (const float*)d_in[12];
    const float* b2b = (const float*)d_in[13];
    const float* b2m = (const float*)d_in[14];
    const float* b2v = (const float*)d_in[15];
    const float* r2w = (const float*)d_in[16];
    const float* r2g = (const float*)d_in[17];
    const float* r2b = (const float*)d_in[18];
    const float* r2m = (const float*)d_in[19];
    const float* r2v = (const float*)d_in[20];
    const float* w3  = (const float*)d_in[21];
    const float* b3g = (const float*)d_in[22];
    const float* b3b = (const float*)d_in[23];
    const float* b3m = (const float*)d_in[24];
    const float* b3v = (const float*)d_in[25];
    float* out = (float*)d_out;

    char* ws = (char*)d_ws;
    unsigned short* h1c  = (unsigned short*)(ws + 0);            // 77,070,336  bf16 NHWC 56x56
    float*          h2c  = (float*)         (ws + 77070336UL);   // 38,535,168  fp32 NHWC 28x28
    unsigned short* h2b  = (unsigned short*)(ws + 115605504UL);  // 19,267,584  bf16 NHWC 28x28
    unsigned short* wb1  = (unsigned short*)(ws + 134873088UL);  // 42,467,328
    unsigned short* wb2r = (unsigned short*)(ws + 177340416UL);  // 10,616,832
    float*          wt1  = (float*)         (ws + 187957248UL);  //     36,864
    unsigned short* wb2c = (unsigned short*)(ws + 187994112UL);  //    294,912
    unsigned short* wb3c = (unsigned short*)(ws + 188289024UL);  //  1,179,648
    // total 189,468,672 B

    wprep_bf16_k<<<8192, 256, 0, stream>>>(r1w, wb1, (long)64 * 192 * 9 * 192);
    wprep_bf16_k<<<2048, 256, 0, stream>>>(r2w, wb2r, (long)16 * 192 * 9 * 192);
    wprep_tap_k<<<576, 256, 0, stream>>>(w2, wb2c, 192);
    wprep_tap_k<<<2304, 256, 0, stream>>>(w3, wb3c, 768);
    wprep_wt1_k<<<36, 256, 0, stream>>>(w1, wt1);

    conv1_k<<<64 * 56, 192, 0, stream>>>(x, wt1, b1g, b1b, b1m, b1v, h1c);
    region_mfma2_k<0><<<64 * 32, 256, 0, stream>>>(h1c, h1c, wb1, r1g, r1b, r1m, r1v, 8, 56);
    conv2_mfma_k<<<64 * 7, 256, 0, stream>>>(h1c, wb2c, b2g, b2b, b2m, b2v, h2c);
    region_mfma2_k<1><<<16 * 32, 256, 0, stream>>>(h2c, h2b, wb2r, r2g, r2b, r2m, r2v, 4, 28);
    conv3_mfma_k<<<64 * 6, 256, 0, stream>>>(h2b, wb3c, b3g, b3b, b3m, b3v, out);
}

// Round 6
// 867.375 us; speedup vs baseline: 5.1788x; 1.1377x over previous
//
#include <hip/hip_runtime.h>
#include <hip/hip_bf16.h>
#include <math.h>

#define EPSBN 1e-5f

typedef short short8 __attribute__((ext_vector_type(8)));
typedef short short4v __attribute__((ext_vector_type(4)));
typedef float floatx4 __attribute__((ext_vector_type(4)));

__device__ __forceinline__ float gelu_f(float x) {
    return 0.5f * x * (1.0f + erff(x * 0.70710678118654752f));
}

__device__ __forceinline__ unsigned short f2bf(float f) {
    union { float f; unsigned int u; } c; c.f = f;
    unsigned int u = c.u;
    unsigned int r = (u + 0x7FFFu + ((u >> 16) & 1u)) >> 16;   // RNE
    return (unsigned short)r;
}

__device__ __forceinline__ float bf2f(unsigned short h) {
    union { unsigned int u; float f; } c; c.u = ((unsigned int)h) << 16;
    return c.f;
}

// ---------------- weight preps ----------------
// region weights: [G][oc][ic][3][3] fp32 -> [G][oc][t][ic] bf16
__global__ void wprep_bf16_k(const float* __restrict__ w, unsigned short* __restrict__ wb,
                             long total) {
    for (long o = (long)blockIdx.x * blockDim.x + threadIdx.x; o < total;
         o += (long)gridDim.x * blockDim.x) {
        int ic = (int)(o % 192); long t0 = o / 192;
        int t = (int)(t0 % 9); long t1 = t0 / 9;
        int oc = (int)(t1 % 192); long g = t1 / 192;
        wb[o] = f2bf(w[(((size_t)g * 192 + oc) * 192 + ic) * 9 + t]);
    }
}

// downsample weights: [OC][192][2][2] fp32 -> [t4][OC][192] bf16
__global__ void wprep_tap_k(const float* __restrict__ w, unsigned short* __restrict__ wb,
                            int OC) {
    long total = (long)4 * OC * 192;
    for (long o = (long)blockIdx.x * blockDim.x + threadIdx.x; o < total;
         o += (long)gridDim.x * blockDim.x) {
        int ic = (int)(o % 192); long t0 = o / 192;
        int oc = (int)(t0 % OC); int t = (int)(t0 / OC);
        wb[o] = f2bf(w[((size_t)oc * 192 + ic) * 4 + t]);
    }
}

// conv1 weights: [192][48] -> [48][192] fp32
__global__ void wprep_wt1_k(const float* __restrict__ w, float* __restrict__ wt) {
    int o = blockIdx.x * 256 + threadIdx.x;
    if (o < 9216) {
        int oc = o % 192, k = o / 192;
        wt[o] = w[oc * 48 + k];
    }
}

// ---------------- conv1: 3->192, 4x4 stride 4, BN+GELU, NHWC bf16 out ----------------
__global__ __launch_bounds__(192) void conv1_k(
        const float* __restrict__ x, const float* __restrict__ wt1,
        const float* __restrict__ bg, const float* __restrict__ bb,
        const float* __restrict__ bm, const float* __restrict__ bv,
        unsigned short* __restrict__ h1c) {
    __shared__ float xs[3][4][224];
    int b = blockIdx.x / 56, oy = blockIdx.x % 56;
    int tid = threadIdx.x;
    for (int i = tid; i < 2688; i += 192) {
        int col = i % 224, r = (i / 224) % 4, c = i / 896;
        xs[c][r][col] = x[(((size_t)b * 3 + c) * 224 + 4 * oy + r) * 224 + col];
    }
    float w[48];
    #pragma unroll
    for (int k = 0; k < 48; k++) w[k] = wt1[k * 192 + tid];
    float inv = bg[tid] * rsqrtf(bv[tid] + EPSBN);
    float bet = bb[tid] - bm[tid] * inv;
    __syncthreads();
    for (int ox = 0; ox < 56; ox++) {
        float a = 0.f;
        #pragma unroll
        for (int c = 0; c < 3; c++) {
            #pragma unroll
            for (int ky = 0; ky < 4; ky++) {
                float4 v = *(const float4*)&xs[c][ky][4 * ox];
                const float* wk = &w[(c * 4 + ky) * 4];
                a += v.x * wk[0] + v.y * wk[1] + v.z * wk[2] + v.w * wk[3];
            }
        }
        h1c[(((size_t)b * 56 + oy) * 56 + ox) * 192 + tid] = f2bf(gelu_f(a * inv + bet));
    }
}

// ---------------- region conv via MFMA v3: wave = 2 tiles x 128px x 48oc ----------------
// block = (g, batch-pair): 4 waves, each wave covers BOTH tiles (8 m-frags) and a distinct
// 48-oc quarter (3 n-frags). Block reads the 663KB weight slab exactly once ->
// global 128 B/MFMA (L2 cap ~53%), LDS 341 B/MFMA. Residual re-read from global (L2-hot),
// removing the conflicted scalar-LDS epilogue reads. XCD swizzle keeps slab L2-resident.
#define RST 200
#define TILE_SH (81 * RST)
template<int INF32>
__global__ __launch_bounds__(256, 2) void region_mfma3_k(
        const void* __restrict__ inbuf, void* __restrict__ outbuf,
        const unsigned short* __restrict__ wb,
        const float* __restrict__ pg, const float* __restrict__ pb,
        const float* __restrict__ pm, const float* __restrict__ pv,
        int gw, int W) {
    __shared__ unsigned short lds[2 * TILE_SH];   // 64,800 B -> 2 blocks/CU
    const int raw = blockIdx.x;
    const int g = (raw & 7) + 8 * (raw >> 8);
    const int bp = (raw >> 3) & 31;
    const int b0 = bp * 2;
    const int gy = g / gw, gx = g % gw;
    const int Y0 = gy * 7, X0 = gx * 7;
    const int tid = threadIdx.x;
    const int lane = tid & 63;
    const int wid = tid >> 6;
    const int quad = lane >> 4;
    const int l15 = lane & 15;

    const size_t tsz = (size_t)W * W * 192;
    const size_t slab0 = (size_t)b0 * tsz;

    // halo zero (perimeter cells), vectorized
    for (int i = tid; i < 1536; i += 256) {
        int tI = i / 768, rem = i % 768, h = rem / 24, ch = rem % 24;
        int cell;
        if (h < 9) cell = h;
        else if (h < 18) cell = 72 + (h - 9);
        else { int h2 = h - 18; cell = (1 + (h2 >> 1)) * 9 + ((h2 & 1) * 8); }
        *(short8*)&lds[tI * TILE_SH + cell * RST + ch * 8] = (short8)0;
    }
    // interior fill, b128 per lane
    for (int i = tid; i < 2352; i += 256) {
        int tI = i / 1176, rem = i % 1176, p = rem / 24, ch = rem % 24;
        int y = p / 7, xx = p % 7;
        size_t poff = slab0 + (size_t)tI * tsz + ((size_t)(Y0 + y) * W + (X0 + xx)) * 192 + ch * 8;
        short8 v;
        if (INF32) {
            const float* s4 = (const float*)inbuf + poff;
            float4 a = *(const float4*)s4;
            float4 b2 = *(const float4*)(s4 + 4);
            v[0] = (short)f2bf(a.x);  v[1] = (short)f2bf(a.y);
            v[2] = (short)f2bf(a.z);  v[3] = (short)f2bf(a.w);
            v[4] = (short)f2bf(b2.x); v[5] = (short)f2bf(b2.y);
            v[6] = (short)f2bf(b2.z); v[7] = (short)f2bf(b2.w);
        } else {
            v = *(const short8*)((const unsigned short*)inbuf + poff);
        }
        *(short8*)&lds[tI * TILE_SH + ((y + 1) * 9 + (xx + 1)) * RST + ch * 8] = v;
    }
    __syncthreads();

    // per-lane m-frag pixel coords (per tile; same for both tiles)
    int pyv[4], pxv[4];
    #pragma unroll
    for (int f = 0; f < 4; f++) {
        int p = f * 16 + l15; if (p > 48) p = 48;
        pyv[f] = p / 7; pxv[f] = p % 7;
    }
    // weight offsets: oc = wid*48 + nt*16 + l15
    int woff[3];
    #pragma unroll
    for (int nt = 0; nt < 3; nt++)
        woff[nt] = (wid * 48 + nt * 16 + l15) * 1728 + quad * 8;
    const unsigned short* wbg = wb + (size_t)g * 331776;

    floatx4 acc[8][3];
    #pragma unroll
    for (int m = 0; m < 8; m++)
        #pragma unroll
        for (int nt = 0; nt < 3; nt++) acc[m][nt] = (floatx4)0.f;

    for (int t = 0; t < 9; t++) {
        const int ky = t / 3, kx = t % 3;
        int ca[8];
        #pragma unroll
        for (int f = 0; f < 4; f++) {
            int cell = ((pyv[f] + ky) * 9 + (pxv[f] + kx)) * RST + quad * 8;
            ca[f] = cell;
            ca[4 + f] = TILE_SH + cell;
        }
        const int toff = t * 192;
        #pragma unroll
        for (int s = 0; s < 6; s++) {
            const int ic0 = s * 32;
            short8 wf[3];
            #pragma unroll
            for (int nt = 0; nt < 3; nt++)
                wf[nt] = *(const short8*)(wbg + woff[nt] + toff + ic0);
            short8 pf[8];
            #pragma unroll
            for (int m = 0; m < 8; m++)
                pf[m] = *(const short8*)&lds[ca[m] + ic0];
            #pragma unroll
            for (int m = 0; m < 8; m++)
                #pragma unroll
                for (int nt = 0; nt < 3; nt++)
                    acc[m][nt] = __builtin_amdgcn_mfma_f32_16x16x32_bf16(pf[m], wf[nt], acc[m][nt], 0, 0, 0);
        }
    }

    // epilogue: C row = pixel (f*16 + quad*4 + r), col = oc (l15). Residual from global.
    #pragma unroll
    for (int nt = 0; nt < 3; nt++) {
        int oc = wid * 48 + nt * 16 + l15;
        float inv = pg[g * 192 + oc] * rsqrtf(pv[g * 192 + oc] + EPSBN);
        float bet = pb[g * 192 + oc] - pm[g * 192 + oc] * inv;
        #pragma unroll
        for (int m = 0; m < 8; m++) {
            const int tI = m >> 3 ? 1 : (m >> 2);   // m/4
            const int f = m & 3;
            const size_t tslab = slab0 + (size_t)tI * tsz;
            unsigned short* outb = (unsigned short*)outbuf + tslab;
            const float* resf = (const float*)inbuf + tslab;
            const unsigned short* resu = (const unsigned short*)inbuf + tslab;
            #pragma unroll
            for (int r = 0; r < 4; r++) {
                int p = f * 16 + quad * 4 + r;
                if (p < 49) {
                    int y = p / 7, xx = p % 7;
                    size_t pix = (size_t)(Y0 + y) * W + (X0 + xx);
                    float res = INF32 ? resf[pix * 192 + oc] : bf2f(resu[pix * 192 + oc]);
                    outb[pix * 192 + oc] = f2bf(gelu_f(acc[m][nt][r] * inv + bet) + res);
                }
            }
        }
    }
}

// ---------------- conv2 via MFMA: 192->192, 2x2 s2, BN+GELU, bf16NHWC -> fp32NHWC ----------
__global__ __launch_bounds__(256) void conv2_mfma_k(
        const unsigned short* __restrict__ h1c, const unsigned short* __restrict__ wb,
        const float* __restrict__ bg, const float* __restrict__ bb,
        const float* __restrict__ bm, const float* __restrict__ bv,
        float* __restrict__ h2c) {
    __shared__ unsigned short lds[2 * 112 * 40];
    const int b = blockIdx.x / 7;
    const int oy0 = (blockIdx.x % 7) * 4;
    const int tid = threadIdx.x;
    const int lane = tid & 63;
    const int wid = tid >> 6;
    const int quad = lane >> 4;
    const int l15 = lane & 15;

    floatx4 acc[7][3];
    #pragma unroll
    for (int mt = 0; mt < 7; mt++)
        #pragma unroll
        for (int nt = 0; nt < 3; nt++) acc[mt][nt] = (floatx4)0.f;

    for (int ky = 0; ky < 2; ky++) {
        for (int c = 0; c < 6; c++) {
            __syncthreads();
            for (int i = tid; i < 1792; i += 256) {
                int icq = i & 7, kx = (i >> 3) & 1, p = i >> 4;
                int oy = oy0 + p / 28, ox = p % 28;
                int iy = 2 * oy + ky, ix = 2 * ox + kx;
                const unsigned short* src =
                    h1c + (((size_t)b * 56 + iy) * 56 + ix) * 192 + c * 32 + icq * 4;
                *(short4v*)(&lds[kx * 4480 + p * 40 + icq * 4]) = *(const short4v*)src;
            }
            __syncthreads();
            #pragma unroll
            for (int kx = 0; kx < 2; kx++) {
                const int t = ky * 2 + kx;
                short8 wf[3];
                #pragma unroll
                for (int nt = 0; nt < 3; nt++) {
                    int oc = wid * 48 + nt * 16 + l15;
                    wf[nt] = *(const short8*)(wb + ((size_t)(t * 192 + oc)) * 192 + c * 32 + quad * 8);
                }
                #pragma unroll
                for (int mt = 0; mt < 7; mt++) {
                    short8 ap = *(const short8*)(&lds[kx * 4480 + (mt * 16 + l15) * 40 + quad * 8]);
                    #pragma unroll
                    for (int nt = 0; nt < 3; nt++)
                        acc[mt][nt] = __builtin_amdgcn_mfma_f32_16x16x32_bf16(ap, wf[nt], acc[mt][nt], 0, 0, 0);
                }
            }
        }
    }
    #pragma unroll
    for (int nt = 0; nt < 3; nt++) {
        int oc = wid * 48 + nt * 16 + l15;
        float inv = bg[oc] * rsqrtf(bv[oc] + EPSBN);
        float bet = bb[oc] - bm[oc] * inv;
        #pragma unroll
        for (int mt = 0; mt < 7; mt++) {
            #pragma unroll
            for (int r = 0; r < 4; r++) {
                int p = mt * 16 + quad * 4 + r;
                int oy = oy0 + p / 28, ox = p % 28;
                h2c[(((size_t)b * 28 + oy) * 28 + ox) * 192 + oc] = gelu_f(acc[mt][nt][r] * inv + bet);
            }
        }
    }
}

// ---------------- conv3 via MFMA: 192->768, 2x2 s2, BN, bf16NHWC -> out (B,196,768) ----
__global__ __launch_bounds__(256) void conv3_mfma_k(
        const unsigned short* __restrict__ h2b, const unsigned short* __restrict__ wb,
        const float* __restrict__ bg, const float* __restrict__ bb,
        const float* __restrict__ bm, const float* __restrict__ bv,
        float* __restrict__ out) {
    __shared__ unsigned short lds[2 * 112 * 40];
    const int bid = blockIdx.x;
    const int b = bid / 6;
    const int s = (bid % 6) / 3;
    const int octile = bid % 3;
    const int y0 = s * 7;
    const int tid = threadIdx.x;
    const int lane = tid & 63;
    const int wid = tid >> 6;
    const int quad = lane >> 4;
    const int l15 = lane & 15;

    floatx4 acc[7][4];
    #pragma unroll
    for (int mt = 0; mt < 7; mt++)
        #pragma unroll
        for (int nt = 0; nt < 4; nt++) acc[mt][nt] = (floatx4)0.f;

    for (int ky = 0; ky < 2; ky++) {
        for (int c = 0; c < 6; c++) {
            __syncthreads();
            for (int i = tid; i < 1568; i += 256) {
                int icq = i & 7, kx = (i >> 3) & 1, p = i >> 4;
                int oy = y0 + p / 14, ox = p % 14;
                int iy = 2 * oy + ky, ix = 2 * ox + kx;
                const unsigned short* src =
                    h2b + (((size_t)b * 28 + iy) * 28 + ix) * 192 + c * 32 + icq * 4;
                *(short4v*)(&lds[kx * 4480 + p * 40 + icq * 4]) = *(const short4v*)src;
            }
            __syncthreads();
            #pragma unroll
            for (int kx = 0; kx < 2; kx++) {
                const int t = ky * 2 + kx;
                short8 wf[4];
                #pragma unroll
                for (int nt = 0; nt < 4; nt++) {
                    int oc = octile * 256 + wid * 64 + nt * 16 + l15;
                    wf[nt] = *(const short8*)(wb + ((size_t)(t * 768 + oc)) * 192 + c * 32 + quad * 8);
                }
                #pragma unroll
                for (int mt = 0; mt < 7; mt++) {
                    int p = mt * 16 + l15; if (p > 97) p = 97;
                    short8 ap = *(const short8*)(&lds[kx * 4480 + p * 40 + quad * 8]);
                    #pragma unroll
                    for (int nt = 0; nt < 4; nt++)
                        acc[mt][nt] = __builtin_amdgcn_mfma_f32_16x16x32_bf16(ap, wf[nt], acc[mt][nt], 0, 0, 0);
                }
            }
        }
    }
    #pragma unroll
    for (int nt = 0; nt < 4; nt++) {
        int oc = octile * 256 + wid * 64 + nt * 16 + l15;
        float inv = bg[oc] * rsqrtf(bv[oc] + EPSBN);
        float bet = bb[oc] - bm[oc] * inv;
        #pragma unroll
        for (int mt = 0; mt < 7; mt++) {
            #pragma unroll
            for (int r = 0; r < 4; r++) {
                int p = mt * 16 + quad * 4 + r;
                if (p < 98) {
                    int oy = y0 + p / 14, ox = p % 14;
                    out[((size_t)b * 196 + oy * 14 + ox) * 768 + oc] = acc[mt][nt][r] * inv + bet;
                }
            }
        }
    }
}

extern "C" void kernel_launch(void* const* d_in, const int* in_sizes, int n_in,
                              void* d_out, int out_size, void* d_ws, size_t ws_size,
                              hipStream_t stream) {
    const float* x   = (const float*)d_in[0];
    const float* w1  = (const float*)d_in[1];
    const float* b1g = (const float*)d_in[2];
    const float* b1b = (const float*)d_in[3];
    const float* b1m = (const float*)d_in[4];
    const float* b1v = (const float*)d_in[5];
    const float* r1w = (const float*)d_in[6];
    const float* r1g = (const float*)d_in[7];
    const float* r1b = (const float*)d_in[8];
    const float* r1m = (const float*)d_in[9];
    const float* r1v = (const float*)d_in[10];
    const float* w2  = (const float*)d_in[11];
    const float* b2g = (const float*)d_in[12];
    const float* b2b = (const float*)d_in[13];
    const float* b2m = (const float*)d_in[14];
    const float* b2v = (const float*)d_in[15];
    const float* r2w = (const float*)d_in[16];
    const float* r2g = (const float*)d_in[17];
    const float* r2b = (const float*)d_in[18];
    const float* r2m = (const float*)d_in[19];
    const float* r2v = (const float*)d_in[20];
    const float* w3  = (const float*)d_in[21];
    const float* b3g = (const float*)d_in[22];
    const float* b3b = (const float*)d_in[23];
    const float* b3m = (const float*)d_in[24];
    const float* b3v = (const float*)d_in[25];
    float* out = (float*)d_out;

    char* ws = (char*)d_ws;
    unsigned short* h1c  = (unsigned short*)(ws + 0);            // 77,070,336  bf16 NHWC 56x56
    float*          h2c  = (float*)         (ws + 77070336UL);   // 38,535,168  fp32 NHWC 28x28
    unsigned short* h2b  = (unsigned short*)(ws + 115605504UL);  // 19,267,584  bf16 NHWC 28x28
    unsigned short* wb1  = (unsigned short*)(ws + 134873088UL);  // 42,467,328
    unsigned short* wb2r = (unsigned short*)(ws + 177340416UL);  // 10,616,832
    float*          wt1  = (float*)         (ws + 187957248UL);  //     36,864
    unsigned short* wb2c = (unsigned short*)(ws + 187994112UL);  //    294,912
    unsigned short* wb3c = (unsigned short*)(ws + 188289024UL);  //  1,179,648
    // total 189,468,672 B

    wprep_bf16_k<<<8192, 256, 0, stream>>>(r1w, wb1, (long)64 * 192 * 9 * 192);
    wprep_bf16_k<<<2048, 256, 0, stream>>>(r2w, wb2r, (long)16 * 192 * 9 * 192);
    wprep_tap_k<<<576, 256, 0, stream>>>(w2, wb2c, 192);
    wprep_tap_k<<<2304, 256, 0, stream>>>(w3, wb3c, 768);
    wprep_wt1_k<<<36, 256, 0, stream>>>(w1, wt1);

    conv1_k<<<64 * 56, 192, 0, stream>>>(x, wt1, b1g, b1b, b1m, b1v, h1c);
    region_mfma3_k<0><<<64 * 32, 256, 0, stream>>>(h1c, h1c, wb1, r1g, r1b, r1m, r1v, 8, 56);
    conv2_mfma_k<<<64 * 7, 256, 0, stream>>>(h1c, wb2c, b2g, b2b, b2m, b2v, h2c);
    region_mfma3_k<1><<<16 * 32, 256, 0, stream>>>(h2c, h2b, wb2r, r2g, r2b, r2m, r2v, 4, 28);
    conv3_mfma_k<<<64 * 6, 256, 0, stream>>>(h2b, wb3c, b3g, b3b, b3m, b3v, out);
}